// Round 6
// baseline (27.891 us; speedup 1.0000x reference)
//
#include <hip/hip_runtime.h>
#include <hip/hip_bf16.h>
#include <math.h>

#define NA 4
#define NT 64
#define NC 8
#define NK 1024
#define NR 8
#define NH 64
#define NW 64

typedef __attribute__((ext_vector_type(8))) short bf16x8;
typedef __attribute__((ext_vector_type(4))) float f32x4;

__device__ __forceinline__ float2 cmul2(float2 a, float2 b) {
    return make_float2(fmaf(a.x, b.x, -a.y * b.y), fmaf(a.x, b.y, a.y * b.x));
}

// ---------------------------------------------------------------------------
// prep: build A_ws (512KB bf16) in MFMA-frag-linear order.
// uint slot t = ((step*2 + mt)*64 + l)*4 + i2 holds the (re,im) bf16 pair for
// m = mt*16 + (l&15), hw = step*16 + (l>>4)*4 + i2.   (step = 16 hw, 4 steps/h? 
// chunk of 16 steps = 4 h-rows)
// ---------------------------------------------------------------------------
__global__ __launch_bounds__(256) void prep_kernel(
    const float* __restrict__ xr, const float* __restrict__ xi,
    const float* __restrict__ mr, const float* __restrict__ mi,
    uint* __restrict__ Aws)
{
    int t = blockIdx.x * 256 + threadIdx.x;    // 131072 total
    int step = t >> 9;
    int mt   = (t >> 8) & 1;
    int l    = (t >> 2) & 63;
    int i2   = t & 3;
    int hw = step * 16 + ((l >> 4) << 2) + i2;
    int m  = (mt << 4) + (l & 15);
    int a = m >> 3, c = m & 7;
    float xre = xr[(a << 12) + hw], xim = xi[(a << 12) + hw];
    float mre = mr[(c << 12) + hw], mim = mi[(c << 12) + hw];
    float re = xre * mre - xim * mim;
    float im = xre * mim + xim * mre;
    __hip_bfloat162 p = __float22bfloat162_rn(make_float2(re, im));
    union { __hip_bfloat162 h; uint u; } cv; cv.h = p;
    Aws[t] = cv.u;
}

// ---------------------------------------------------------------------------
// gemm + fused combine, split-K' for occupancy:
// 512 blocks = (r, 32-k-point tile) x 2 K'-halves (h range [32p, 32p+32)).
// Each block: 8 chunks double-buffered, 8 waves = 2 nsub x 4 kq.
// Partial phi/dcf-contracted results atomicAdd'ed into pre-zeroed out.
// ---------------------------------------------------------------------------
__global__ __launch_bounds__(512, 4) void gemm_kernel(
    const uint* __restrict__ Aws, const float* __restrict__ trj,
    const float* __restrict__ phi, const float* __restrict__ dcf,
    const int* __restrict__ sidx, float* __restrict__ out)
{
    __shared__ uint lds[16384];   // 64KB: two 32KB chunk buffers (reused by epilogue)
    int b = blockIdx.x;           // 512
    int p  = b & 1;               // K'-half
    int bb = b >> 1;              // 256: (r, k-tile)
    int tid = threadIdx.x;
    int w = tid >> 6, l = tid & 63;
    int nsub = w & 1, kq = w >> 1;
    int lg = l >> 4, ln = l & 15;
    int r = bb >> 5;
    int kp = ((bb & 31) << 5) + (nsub << 4) + ln;   // k-point 0..1023

    // issue chunk-0 staging first so its latency hides under the sincos prologue
    const uint* gsrc0 = Aws + (p << 16);            // p*8 chunks * 8192 uints
    #pragma unroll
    for (int q = 0; q < 4; ++q) {
        __builtin_amdgcn_global_load_lds(
            (const __attribute__((address_space(1))) void*)(gsrc0 + (w*4 + q)*256 + l*4),
            (__attribute__((address_space(3))) void*)(lds + (w*4 + q)*256),
            16, 0, 0);
    }

    float t0 = trj[(r << 11) + kp];
    float t1 = trj[(r << 11) + 1024 + kp];

    // ewb[i] = exp(-i*t1*(w-32)) for w = lg*4 + i;  per-j factor st16 = exp(-i*16*t1)
    float sv, cv;
    float2 ewb[4], st1, st16, st4h, ehc;
    int w0 = lg << 2;
    sincosf(t1 * (float)(32 - w0), &sv, &cv); ewb[0] = make_float2(cv, sv);
    sincosf(-t1, &sv, &cv);         st1  = make_float2(cv, sv);
    sincosf(-16.0f * t1, &sv, &cv); st16 = make_float2(cv, sv);
    ewb[1] = cmul2(ewb[0], st1);
    ewb[2] = cmul2(ewb[1], st1);
    ewb[3] = cmul2(ewb[2], st1);
    // Eh: this wave sees h = 32p + ch*4 + kq
    sincosf(t0 * (float)(32 - kq - 32 * p), &sv, &cv); ehc = make_float2(cv, sv);
    sincosf(-4.0f * t0, &sv, &cv); st4h = make_float2(cv, sv);

    f32x4 acc0 = {0.f, 0.f, 0.f, 0.f}, acc1 = acc0;

    for (int ch = 0; ch < 8; ++ch) {
        int cur = ch & 1;
        __syncthreads();   // current chunk resident, prev buffer free
        if (ch < 7) {
            const uint* gsrc = gsrc0 + (ch + 1) * 8192;
            uint* ldst = lds + (cur ? 0 : 8192);
            #pragma unroll
            for (int q = 0; q < 4; ++q) {
                __builtin_amdgcn_global_load_lds(
                    (const __attribute__((address_space(1))) void*)(gsrc + (w*4 + q)*256 + l*4),
                    (__attribute__((address_space(3))) void*)(ldst + (w*4 + q)*256),
                    16, 0, 0);
            }
        }
        const uint* bufc = lds + (cur ? 8192 : 0);
        float2 g = ehc;    // = ehc * st16^j, advanced per j
        #pragma unroll
        for (int j = 0; j < 4; ++j) {
            int ls = kq * 4 + j;
            bf16x8 a0 = *(const bf16x8*)(bufc + (ls*2 + 0)*256 + l*4);
            bf16x8 a1 = *(const bf16x8*)(bufc + (ls*2 + 1)*256 + l*4);
            union { uint u[4]; bf16x8 v; } bf;
            #pragma unroll
            for (int i = 0; i < 4; ++i) {
                float2 e2 = cmul2(g, ewb[i]);
                __hip_bfloat162 pk = __float22bfloat162_rn(make_float2(e2.x, -e2.y));
                union { __hip_bfloat162 h; uint u; } cu; cu.h = pk;
                bf.u[i] = cu.u;
            }
            acc0 = __builtin_amdgcn_mfma_f32_16x16x32_bf16(a0, bf.v, acc0, 0, 0, 0);
            acc1 = __builtin_amdgcn_mfma_f32_16x16x32_bf16(a1, bf.v, acc1, 0, 0, 0);
            g = cmul2(g, st16);
        }
        ehc = cmul2(ehc, st4h);
    }

    // cross-wave K-reduce (4 kq partials per nsub) via LDS, into Fs[32][33]
    __syncthreads();
    float* red = (float*)lds;            // floats 0..4095
    float* Fs  = (float*)lds + 4096;     // floats 4096..5151: Fs[m][kl] stride 33
    int*   ssidx = (int*)((float*)lds + 5504);   // 64 ints
    float* sphi  = (float*)lds + 5576;           // 256 floats, [a][t]
    int base0 = (((kq*2 + nsub)*2 + 0)*64 + l)*4;
    int base1 = (((kq*2 + nsub)*2 + 1)*64 + l)*4;
    #pragma unroll
    for (int g2 = 0; g2 < 4; ++g2) { red[base0 + g2] = acc0[g2]; red[base1 + g2] = acc1[g2]; }
    __syncthreads();
    for (int e = tid; e < 1024; e += 512) {
        float s = red[e] + red[e + 1024] + red[e + 2048] + red[e + 3072];
        int reg = e & 3, lp = (e >> 2) & 63, mt = (e >> 8) & 1, ns = e >> 9;
        int m  = (mt << 4) + ((lp >> 4) << 2) + reg;   // verified C/D row map
        int kl = (ns << 4) + (lp & 15);
        Fs[m * 33 + kl] = s;
    }
    if (tid < 64) ssidx[tid] = sidx[tid];
    else if (tid < 320) sphi[tid - 64] = phi[tid - 64];
    __syncthreads();

    // fused combine (partial over this K'-half): atomicAdd into pre-zeroed out.
    int e  = tid & 255, tpar = tid >> 8;
    int c  = e >> 5, kl = e & 31;
    int kg = ((bb & 31) << 5) + kl;
    float dv = dcf[(r << 10) + kg] * 0.03125f;   // scale = 2/sqrt(64*64)
    const float* Fsp = Fs + c * 33 + kl;
    for (int t = tpar; t < NT; t += 2) {
        if (ssidx[t] != r) continue;
        float s = 0.f;
        #pragma unroll
        for (int a = 0; a < 4; ++a)
            s = fmaf(sphi[a * 64 + t], Fsp[a * 264], s);   // 264 = 8*33
        atomicAdd(out + (t << 13) + (c << 10) + kg, s * dv);
    }
}

// ---------------- fallback (proven round-3 path, no ws needed) --------------
__global__ __launch_bounds__(256) void ndft_atomic_kernel(
    const float* __restrict__ xr, const float* __restrict__ xi,
    const float* __restrict__ mr, const float* __restrict__ mi,
    const float* __restrict__ trj,
    const float* __restrict__ phi, const float* __restrict__ dcf,
    const int* __restrict__ sidx, float* __restrict__ out)
{
    __shared__ float2 simg[NH * NW];
    int b = blockIdx.x;
    int kq = b & 3, c = (b >> 2) & 7, a = (b >> 5) & 3, r = b >> 7;
    int tid = threadIdx.x;
    for (int i = tid; i < NH * NW; i += 256) {
        float xre = xr[(a << 12) + i], xim = xi[(a << 12) + i];
        float mre = mr[(c << 12) + i], mim = mi[(c << 12) + i];
        simg[i] = make_float2(xre * mre - xim * mim, xre * mim + xim * mre);
    }
    __syncthreads();
    int k = (kq << 8) + tid;
    float t0 = trj[(r << 11) + k];
    float t1 = trj[(r << 11) + 1024 + k];
    float sv, cv;
    sincosf(-t1, &sv, &cv);        float2 ewb = make_float2(cv, sv);
    sincosf(32.0f * t1, &sv, &cv); float2 ews = make_float2(cv, sv);
    sincosf(-t0, &sv, &cv);        float2 ehb = make_float2(cv, sv);
    sincosf(32.0f * t0, &sv, &cv); float2 ehc = make_float2(cv, sv);
    float accx = 0.f;
    for (int h0 = 0; h0 < NH; h0 += 4) {
        float2 s0 = make_float2(0.f, 0.f), s1 = s0, s2 = s0, s3 = s0;
        const float2* i0 = simg + (h0 << 6);
        float2 ewc = ews;
        #pragma unroll 8
        for (int w = 0; w < NW; ++w) {
            float2 v0 = i0[w], v1 = i0[w+64], v2 = i0[w+128], v3 = i0[w+192];
            s0.x = fmaf(v0.x, ewc.x, fmaf(-v0.y, ewc.y, s0.x));
            s0.y = fmaf(v0.x, ewc.y, fmaf( v0.y, ewc.x, s0.y));
            s1.x = fmaf(v1.x, ewc.x, fmaf(-v1.y, ewc.y, s1.x));
            s1.y = fmaf(v1.x, ewc.y, fmaf( v1.y, ewc.x, s1.y));
            s2.x = fmaf(v2.x, ewc.x, fmaf(-v2.y, ewc.y, s2.x));
            s2.y = fmaf(v2.x, ewc.y, fmaf( v2.y, ewc.x, s2.y));
            s3.x = fmaf(v3.x, ewc.x, fmaf(-v3.y, ewc.y, s3.x));
            s3.y = fmaf(v3.x, ewc.y, fmaf( v3.y, ewc.x, s3.y));
            ewc = cmul2(ewc, ewb);
        }
        float2 e0 = ehc, e1 = cmul2(e0, ehb), e2 = cmul2(e1, ehb), e3 = cmul2(e2, ehb);
        ehc = cmul2(e3, ehb);
        accx = fmaf(s0.x, e0.x, fmaf(-s0.y, e0.y, accx));
        accx = fmaf(s1.x, e1.x, fmaf(-s1.y, e1.y, accx));
        accx = fmaf(s2.x, e2.x, fmaf(-s2.y, e2.y, accx));
        accx = fmaf(s3.x, e3.x, fmaf(-s3.y, e3.y, accx));
    }
    float d = dcf[(r << 10) + k] * 0.03125f;
    for (int t = 0; t < NT; ++t) {
        if (sidx[t] == r) atomicAdd(out + (t << 13) + (c << 10) + k, phi[a*64 + t] * d * accx);
    }
}

extern "C" void kernel_launch(void* const* d_in, const int* in_sizes, int n_in,
                              void* d_out, int out_size, void* d_ws, size_t ws_size,
                              hipStream_t stream)
{
    const float* x_re   = (const float*)d_in[0];
    const float* x_im   = (const float*)d_in[1];
    const float* mps_re = (const float*)d_in[2];
    const float* mps_im = (const float*)d_in[3];
    const float* phi    = (const float*)d_in[4];
    const float* dcf    = (const float*)d_in[5];
    const float* trj    = (const float*)d_in[6];
    const int*   sidx   = (const int*)d_in[7];
    float* out = (float*)d_out;

    const size_t A_bytes = 512 * 1024;   // bf16 A matrix

    hipMemsetAsync(d_out, 0, (size_t)out_size * sizeof(float), stream);
    if (ws_size >= A_bytes) {
        uint* Aws = (uint*)d_ws;
        hipLaunchKernelGGL(prep_kernel, dim3(512), dim3(256), 0, stream,
                           x_re, x_im, mps_re, mps_im, Aws);
        hipLaunchKernelGGL(gemm_kernel, dim3(512), dim3(512), 0, stream,
                           Aws, trj, phi, dcf, sidx, out);
    } else {
        hipLaunchKernelGGL(ndft_atomic_kernel, dim3(1024), dim3(256), 0, stream,
                           x_re, x_im, mps_re, mps_im, trj, phi, dcf, sidx, out);
    }
}

// Round 7
// 25.065 us; speedup vs baseline: 1.1127x; 1.1127x over previous
//
#include <hip/hip_runtime.h>
#include <hip/hip_bf16.h>
#include <math.h>

#define NA 4
#define NT 64
#define NC 8
#define NK 1024
#define NR 8
#define NH 64
#define NW 64

typedef __attribute__((ext_vector_type(8))) short bf16x8;
typedef __attribute__((ext_vector_type(4))) float f32x4;

__device__ __forceinline__ float2 cmul2(float2 a, float2 b) {
    return make_float2(fmaf(a.x, b.x, -a.y * b.y), fmaf(a.x, b.y, a.y * b.x));
}

// native-trig sincos: v_sin_f32/v_cos_f32 path (~3 ops each), NOT the ocml
// library call. |x| <= ~101 rad (16 revolutions) -> phase err ~2e-4 rad,
// invisible under bf16 (0.4% relative) quantization.
__device__ __forceinline__ void fast_sc(float x, float* s, float* c) {
    *s = __sinf(x);
    *c = __cosf(x);
}

// ---------------------------------------------------------------------------
// prep: build A_ws (512KB bf16) in MFMA-frag-linear order.
// uint slot t = ((step*2 + mt)*64 + l)*4 + i2 holds the (re,im) bf16 pair for
// m = mt*16 + (l&15), hw = step*16 + (l>>4)*4 + i2.
// ---------------------------------------------------------------------------
__global__ __launch_bounds__(256) void prep_kernel(
    const float* __restrict__ xr, const float* __restrict__ xi,
    const float* __restrict__ mr, const float* __restrict__ mi,
    uint* __restrict__ Aws)
{
    int t = blockIdx.x * 256 + threadIdx.x;    // 131072 total
    int step = t >> 9;
    int mt   = (t >> 8) & 1;
    int l    = (t >> 2) & 63;
    int i2   = t & 3;
    int hw = step * 16 + ((l >> 4) << 2) + i2;
    int m  = (mt << 4) + (l & 15);
    int a = m >> 3, c = m & 7;
    float xre = xr[(a << 12) + hw], xim = xi[(a << 12) + hw];
    float mre = mr[(c << 12) + hw], mim = mi[(c << 12) + hw];
    float re = xre * mre - xim * mim;
    float im = xre * mim + xim * mre;
    __hip_bfloat162 p = __float22bfloat162_rn(make_float2(re, im));
    union { __hip_bfloat162 h; uint u; } cv; cv.h = p;
    Aws[t] = cv.u;
}

// ---------------------------------------------------------------------------
// gemm (split-K'): Re(F)_p[m][rk] = sum_{k' in half p} A[m][k'] * B[rk][k'],
// B generated in-register with native trig. 512 blocks = (r, k-tile32) x 2
// K'-halves; 8 waves = 2 nsub x 4 kq; 8 chunks double-buffered.
// Writes Fre[p][32][8192] partials (no atomics).
// ---------------------------------------------------------------------------
__global__ __launch_bounds__(512, 4) void gemm_kernel(
    const uint* __restrict__ Aws, const float* __restrict__ trj,
    float* __restrict__ Fre)
{
    __shared__ uint lds[16384];   // 64KB: two 32KB chunk buffers
    int b = blockIdx.x;           // 512
    int p  = b & 1;               // K'-half (h in [32p, 32p+32))
    int bb = b >> 1;              // 256: (r, k-tile)
    int tid = threadIdx.x;
    int w = tid >> 6, l = tid & 63;
    int nsub = w & 1, kq = w >> 1;
    int lg = l >> 4, ln = l & 15;
    int r = bb >> 5;
    int kp = ((bb & 31) << 5) + (nsub << 4) + ln;   // k-point 0..1023

    // issue chunk-0 staging first: latency hides under the trig prologue
    const uint* gsrc0 = Aws + (p << 16);            // p * 8 chunks * 8192 uints
    #pragma unroll
    for (int q = 0; q < 4; ++q) {
        __builtin_amdgcn_global_load_lds(
            (const __attribute__((address_space(1))) void*)(gsrc0 + (w*4 + q)*256 + l*4),
            (__attribute__((address_space(3))) void*)(lds + (w*4 + q)*256),
            16, 0, 0);
    }

    float t0 = trj[(r << 11) + kp];
    float t1 = trj[(r << 11) + 1024 + kp];

    // ewb[i] = exp(-i*t1*(w-32)) for w = lg*4 + i;  st16 = exp(-i*16*t1)
    float sv, cv;
    float2 ewb[4], st1, st16, st4h, ehc;
    int w0 = lg << 2;
    fast_sc(t1 * (float)(32 - w0), &sv, &cv); ewb[0] = make_float2(cv, sv);
    fast_sc(-t1, &sv, &cv);         st1  = make_float2(cv, sv);
    fast_sc(-16.0f * t1, &sv, &cv); st16 = make_float2(cv, sv);
    ewb[1] = cmul2(ewb[0], st1);
    ewb[2] = cmul2(ewb[1], st1);
    ewb[3] = cmul2(ewb[2], st1);
    // Eh: this wave sees h = 32p + ch*4 + kq
    fast_sc(t0 * (float)(32 - kq - 32 * p), &sv, &cv); ehc = make_float2(cv, sv);
    fast_sc(-4.0f * t0, &sv, &cv); st4h = make_float2(cv, sv);

    f32x4 acc0 = {0.f, 0.f, 0.f, 0.f}, acc1 = acc0;

    for (int ch = 0; ch < 8; ++ch) {
        int cur = ch & 1;
        __syncthreads();   // current chunk resident, prev buffer free
        if (ch < 7) {
            const uint* gsrc = gsrc0 + (ch + 1) * 8192;
            uint* ldst = lds + (cur ? 0 : 8192);
            #pragma unroll
            for (int q = 0; q < 4; ++q) {
                __builtin_amdgcn_global_load_lds(
                    (const __attribute__((address_space(1))) void*)(gsrc + (w*4 + q)*256 + l*4),
                    (__attribute__((address_space(3))) void*)(ldst + (w*4 + q)*256),
                    16, 0, 0);
            }
        }
        const uint* bufc = lds + (cur ? 8192 : 0);
        float2 g = ehc;    // = ehc * st16^j, advanced per j
        #pragma unroll
        for (int j = 0; j < 4; ++j) {
            int ls = kq * 4 + j;
            bf16x8 a0 = *(const bf16x8*)(bufc + (ls*2 + 0)*256 + l*4);
            bf16x8 a1 = *(const bf16x8*)(bufc + (ls*2 + 1)*256 + l*4);
            union { uint u[4]; bf16x8 v; } bf;
            #pragma unroll
            for (int i = 0; i < 4; ++i) {
                float2 e2 = cmul2(g, ewb[i]);
                __hip_bfloat162 pk = __float22bfloat162_rn(make_float2(e2.x, -e2.y));
                union { __hip_bfloat162 h; uint u; } cu; cu.h = pk;
                bf.u[i] = cu.u;
            }
            acc0 = __builtin_amdgcn_mfma_f32_16x16x32_bf16(a0, bf.v, acc0, 0, 0, 0);
            acc1 = __builtin_amdgcn_mfma_f32_16x16x32_bf16(a1, bf.v, acc1, 0, 0, 0);
            g = cmul2(g, st16);
        }
        ehc = cmul2(ehc, st4h);
    }

    // cross-wave K-reduce (4 kq partials per nsub) via LDS, write Fre partial
    __syncthreads();
    float* red = (float*)lds;
    int base0 = (((kq*2 + nsub)*2 + 0)*64 + l)*4;
    int base1 = (((kq*2 + nsub)*2 + 1)*64 + l)*4;
    #pragma unroll
    for (int g2 = 0; g2 < 4; ++g2) { red[base0 + g2] = acc0[g2]; red[base1 + g2] = acc1[g2]; }
    __syncthreads();
    for (int e = tid; e < 1024; e += 512) {
        float s = red[e] + red[e + 1024] + red[e + 2048] + red[e + 3072];
        int reg = e & 3, lp = (e >> 2) & 63, mt = (e >> 8) & 1, ns = e >> 9;
        int m  = (mt << 4) + ((lp >> 4) << 2) + reg;   // verified C/D row map
        int rk = (bb << 5) + (ns << 4) + (lp & 15);
        Fre[(p << 18) + (m << 13) + rk] = s;           // p*32*8192 = p<<18
    }
}

__global__ __launch_bounds__(256) void combine_kernel(
    const float* __restrict__ Fre, const float* __restrict__ phi,
    const float* __restrict__ dcf, const int* __restrict__ sidx,
    float* __restrict__ out)
{
    int idx = blockIdx.x * 256 + threadIdx.x;   // T*C*K = 524288
    if (idx >= NT * NC * NK) return;
    int k = idx & 1023;
    int c = (idx >> 10) & 7;
    int t = idx >> 13;
    int r = sidx[t];
    float d = dcf[(r << 10) + k] * 0.03125f;    // scale = 2/sqrt(64*64)
    float acc = 0.f;
    #pragma unroll
    for (int a = 0; a < 4; ++a) {
        float p = phi[a * 64 + t];
        int off = ((((a << 3) + c) << 13) + (r << 10) + k);
        acc = fmaf(p, Fre[off] + Fre[(1 << 18) + off], acc);
    }
    out[idx] = acc * d;
}

// ---------------- fallback (proven round-3 path, no ws needed) --------------
__global__ __launch_bounds__(256) void ndft_atomic_kernel(
    const float* __restrict__ xr, const float* __restrict__ xi,
    const float* __restrict__ mr, const float* __restrict__ mi,
    const float* __restrict__ trj,
    const float* __restrict__ phi, const float* __restrict__ dcf,
    const int* __restrict__ sidx, float* __restrict__ out)
{
    __shared__ float2 simg[NH * NW];
    int b = blockIdx.x;
    int kq = b & 3, c = (b >> 2) & 7, a = (b >> 5) & 3, r = b >> 7;
    int tid = threadIdx.x;
    for (int i = tid; i < NH * NW; i += 256) {
        float xre = xr[(a << 12) + i], xim = xi[(a << 12) + i];
        float mre = mr[(c << 12) + i], mim = mi[(c << 12) + i];
        simg[i] = make_float2(xre * mre - xim * mim, xre * mim + xim * mre);
    }
    __syncthreads();
    int k = (kq << 8) + tid;
    float t0 = trj[(r << 11) + k];
    float t1 = trj[(r << 11) + 1024 + k];
    float sv, cv;
    sincosf(-t1, &sv, &cv);        float2 ewb = make_float2(cv, sv);
    sincosf(32.0f * t1, &sv, &cv); float2 ews = make_float2(cv, sv);
    sincosf(-t0, &sv, &cv);        float2 ehb = make_float2(cv, sv);
    sincosf(32.0f * t0, &sv, &cv); float2 ehc = make_float2(cv, sv);
    float accx = 0.f;
    for (int h0 = 0; h0 < NH; h0 += 4) {
        float2 s0 = make_float2(0.f, 0.f), s1 = s0, s2 = s0, s3 = s0;
        const float2* i0 = simg + (h0 << 6);
        float2 ewc = ews;
        #pragma unroll 8
        for (int w = 0; w < NW; ++w) {
            float2 v0 = i0[w], v1 = i0[w+64], v2 = i0[w+128], v3 = i0[w+192];
            s0.x = fmaf(v0.x, ewc.x, fmaf(-v0.y, ewc.y, s0.x));
            s0.y = fmaf(v0.x, ewc.y, fmaf( v0.y, ewc.x, s0.y));
            s1.x = fmaf(v1.x, ewc.x, fmaf(-v1.y, ewc.y, s1.x));
            s1.y = fmaf(v1.x, ewc.y, fmaf( v1.y, ewc.x, s1.y));
            s2.x = fmaf(v2.x, ewc.x, fmaf(-v2.y, ewc.y, s2.x));
            s2.y = fmaf(v2.x, ewc.y, fmaf( v2.y, ewc.x, s2.y));
            s3.x = fmaf(v3.x, ewc.x, fmaf(-v3.y, ewc.y, s3.x));
            s3.y = fmaf(v3.x, ewc.y, fmaf( v3.y, ewc.x, s3.y));
            ewc = cmul2(ewc, ewb);
        }
        float2 e0 = ehc, e1 = cmul2(e0, ehb), e2 = cmul2(e1, ehb), e3 = cmul2(e2, ehb);
        ehc = cmul2(e3, ehb);
        accx = fmaf(s0.x, e0.x, fmaf(-s0.y, e0.y, accx));
        accx = fmaf(s1.x, e1.x, fmaf(-s1.y, e1.y, accx));
        accx = fmaf(s2.x, e2.x, fmaf(-s2.y, e2.y, accx));
        accx = fmaf(s3.x, e3.x, fmaf(-s3.y, e3.y, accx));
    }
    float d = dcf[(r << 10) + k] * 0.03125f;
    for (int t = 0; t < NT; ++t) {
        if (sidx[t] == r) atomicAdd(out + (t << 13) + (c << 10) + k, phi[a*64 + t] * d * accx);
    }
}

extern "C" void kernel_launch(void* const* d_in, const int* in_sizes, int n_in,
                              void* d_out, int out_size, void* d_ws, size_t ws_size,
                              hipStream_t stream)
{
    const float* x_re   = (const float*)d_in[0];
    const float* x_im   = (const float*)d_in[1];
    const float* mps_re = (const float*)d_in[2];
    const float* mps_im = (const float*)d_in[3];
    const float* phi    = (const float*)d_in[4];
    const float* dcf    = (const float*)d_in[5];
    const float* trj    = (const float*)d_in[6];
    const int*   sidx   = (const int*)d_in[7];
    float* out = (float*)d_out;

    const size_t A_bytes = 512 * 1024;                      // bf16 A matrix
    const size_t F_bytes = 2u * 32 * 8192 * sizeof(float);  // 2MB split-K partials

    if (ws_size >= A_bytes + F_bytes) {
        uint*  Aws = (uint*)d_ws;
        float* Fre = (float*)((char*)d_ws + A_bytes);
        hipLaunchKernelGGL(prep_kernel, dim3(512), dim3(256), 0, stream,
                           x_re, x_im, mps_re, mps_im, Aws);
        hipLaunchKernelGGL(gemm_kernel, dim3(512), dim3(512), 0, stream,
                           Aws, trj, Fre);
        hipLaunchKernelGGL(combine_kernel, dim3(2048), dim3(256), 0, stream,
                           Fre, phi, dcf, sidx, out);
    } else {
        hipMemsetAsync(d_out, 0, (size_t)out_size * sizeof(float), stream);
        hipLaunchKernelGGL(ndft_atomic_kernel, dim3(1024), dim3(256), 0, stream,
                           x_re, x_im, mps_re, mps_im, trj, phi, dcf, sidx, out);
    }
}